// Round 20
// baseline (116.518 us; speedup 1.0000x reference)
//
#include <hip/hip_runtime.h>
#include <hip/hip_bf16.h>
#include <math.h>

typedef __bf16 bf16;
typedef __bf16 bf16x8 __attribute__((ext_vector_type(8)));
typedef __bf16 bf16x4 __attribute__((ext_vector_type(4)));
typedef float  f32x4  __attribute__((ext_vector_type(4)));
typedef float  f32x16 __attribute__((ext_vector_type(16)));
typedef _Float16 f16x8 __attribute__((ext_vector_type(8)));

#define MFMA(a, b, c)   __builtin_amdgcn_mfma_f32_16x16x32_bf16((a), (b), (c), 0, 0, 0)
#define MFMA32(a, b, c) __builtin_amdgcn_mfma_f32_32x32x16_bf16((a), (b), (c), 0, 0, 0)
#define LOG2E 1.4426950408889634f

// ---------------------------------------------------------------------------
// Kernel P: all prep, fully parallel uniform blocks.
//   blocks 0..575      : precast w_qkv^T -> wqT, w_proj^T -> wpT (bf16)
//   blocks 576..8767   : lane-permuted f16 mask table maskp (*log2e)
//   blocks 8768..8953  : pos MLP + lane-permuted f16 pos table (31 rd x 6 h)
// ---------------------------------------------------------------------------
__global__ __launch_bounds__(256) void prep_kernel(
    const float* __restrict__ w_qkv, const float* __restrict__ w_proj,
    const float* __restrict__ mask,
    const float* __restrict__ pw0, const float* __restrict__ pb0,
    const float* __restrict__ g1,  const float* __restrict__ be1,
    const float* __restrict__ w1,  const float* __restrict__ b1,
    const float* __restrict__ g2,  const float* __restrict__ be2,
    const float* __restrict__ w2,  const float* __restrict__ b2,
    const float* __restrict__ g3,  const float* __restrict__ be3,
    const float* __restrict__ w3,  const float* __restrict__ b3,
    bf16* __restrict__ wqT, bf16* __restrict__ wpT,
    _Float16* __restrict__ maskp, _Float16* __restrict__ pos16) {
  __shared__ float posh[31];
  const int blk = blockIdx.x;
  const int t = threadIdx.x;
  if (blk < 576) {
    int idx = blk * 256 + t;
    if (idx < 576 * 192) {
      int c = idx / 192, k = idx % 192;
      wqT[idx] = (bf16)w_qkv[k * 576 + c];
    } else {
      int i2 = idx - 576 * 192;
      int c = i2 / 192, k = i2 % 192;
      wpT[i2] = (bf16)w_proj[k * 192 + c];
    }
  } else if (blk < 8768) {
    size_t e = ((size_t)(blk - 576) * 256 + t) * 2;
    int j  = (int)(e & 15);
    int L  = (int)((e >> 4) & 63);
    int mt = (int)((e >> 10) & 7);
    int qt = (int)((e >> 13) & 7);
    int s  = (int)(e >> 16);
    int q  = qt * 32 + (L & 31);
    int m  = mt * 32 + 16 * (j >> 3) + 8 * ((j >> 2) & 1) + 4 * (L >> 5) + (j & 3);
    const float* src = mask + ((size_t)s * 256 + q) * 256 + m;
    maskp[e]     = (_Float16)(src[0] * LOG2E);
    maskp[e + 1] = (_Float16)(src[1] * LOG2E);
  } else {
    const int pb = blk - 8768;                     // 0..185
    const int rd = pb % 31, h = pb / 31;
    if (t < 31) {
      int i = rd * 31 + t;
      float bh = (float)(i / 31) - 15.0f;
      float bw = (float)(i % 31) - 15.0f;
      float xv[12];
#pragma unroll
      for (int j = 0; j < 12; j++) xv[j] = bh * pw0[j] + bw * pw0[12 + j] + pb0[j];
      const float* G[3]  = {g1, g2, g3};
      const float* BE[3] = {be1, be2, be3};
      const float* W[3]  = {w1, w2, w3};
      const float* BB[3] = {b1, b2, b3};
#pragma unroll
      for (int s = 0; s < 3; s++) {
        float m = 0.f;
#pragma unroll
        for (int j = 0; j < 12; j++) m += xv[j];
        m *= (1.0f / 12.0f);
        float v = 0.f;
#pragma unroll
        for (int j = 0; j < 12; j++) { float d = xv[j] - m; v += d * d; }
        v *= (1.0f / 12.0f);
        float inv = 1.0f / sqrtf(v + 1e-5f);
        float y[12];
#pragma unroll
        for (int j = 0; j < 12; j++) {
          float tt = (xv[j] - m) * inv * G[s][j] + BE[s][j];
          y[j] = tt > 0.f ? tt : 0.f;
        }
        int oc = (s == 2) ? 6 : 12;
        float on[12];
        for (int c = 0; c < oc; c++) {
          float acc = BB[s][c];
#pragma unroll
          for (int j = 0; j < 12; j++) acc += y[j] * W[s][j * oc + c];
          on[c] = acc;
        }
        for (int c = 0; c < 12; c++) xv[c] = (c < oc) ? on[c] : 0.f;
      }
      posh[t] = xv[h];
    }
    __syncthreads();
    for (int e = t; e < 512; e += 256) {
      int L = e >> 3, j = e & 7;
      int idx = (L & 15) - ((j & 3) + 8 * (j >> 2) + 4 * (L >> 5)) + 15;  // 0..30
      pos16[((h * 31 + rd) * 64 + L) * 8 + j] = (_Float16)(posh[idx] * LOG2E);
    }
  }
}

// ---------------------------------------------------------------------------
// Kernel B: QKV GEMM.  grid 256, 512 thr / 8 waves x 32 rows (BM=256, rt=2).
// ---------------------------------------------------------------------------
#define SMEM_G (192 * 200 * 2)

__global__ __launch_bounds__(512) void qkv_gemm_kernel(
    const float* __restrict__ x, const bf16* __restrict__ wqT,
    const float* __restrict__ b_qkv, bf16* __restrict__ qw,
    bf16* __restrict__ kw, bf16* __restrict__ vwT) {
  extern __shared__ char smem[];
  bf16* wt = (bf16*)smem;   // [192 c][200 k]
  const int tid = threadIdx.x;
  const int lane = tid & 63, w = tid >> 6;          // w in 0..7
  const int cI = lane & 15, gI = lane >> 4;
  const int b = blockIdx.x;                         // 256 rows = 1 window
  const int row0 = b * 256 + w * 32;
  const float QSCALE = 0.17677669529663687f * LOG2E;

  bf16x8 afr[2][6];
#pragma unroll
  for (int rt = 0; rt < 2; rt++) {
#pragma unroll
    for (int kk = 0; kk < 6; kk++) {
      const float* p = x + (size_t)(row0 + rt * 16 + cI) * 192 + kk * 32 + gI * 8;
      float4 f0 = *(const float4*)p;
      float4 f1 = *(const float4*)(p + 4);
      bf16x8 a;
      a[0] = (bf16)f0.x; a[1] = (bf16)f0.y; a[2] = (bf16)f0.z; a[3] = (bf16)f0.w;
      a[4] = (bf16)f1.x; a[5] = (bf16)f1.y; a[6] = (bf16)f1.z; a[7] = (bf16)f1.w;
      afr[rt][kk] = a;
    }
  }

#pragma unroll
  for (int mat = 0; mat < 3; mat++) {
    __syncthreads();
#pragma unroll
    for (int it = 0; it < 9; it++) {
      int idx = it * 512 + tid;                     // 192 rows x 24 chunks
      int c = idx / 24, ch = idx % 24;
      bf16x8 v8 = *(const bf16x8*)(wqT + (size_t)(mat * 192 + c) * 192 + ch * 8);
      *(bf16x8*)(wt + c * 200 + ch * 8) = v8;
    }
    __syncthreads();
#pragma unroll
    for (int ct = 0; ct < 12; ct++) {
      bf16x8 wfr[6];
#pragma unroll
      for (int kk = 0; kk < 6; kk++)
        wfr[kk] = *(const bf16x8*)(wt + (ct * 16 + cI) * 200 + kk * 32 + gI * 8);
      if (mat < 2) {
        f32x4 bv4 = *(const f32x4*)(b_qkv + mat * 192 + ct * 16 + gI * 4);
        bf16* dst = (mat == 0) ? qw : kw;
#pragma unroll
        for (int rt = 0; rt < 2; rt++) {
          f32x4 acc = {0.f, 0.f, 0.f, 0.f};
#pragma unroll
          for (int kk = 0; kk < 6; kk++) acc = MFMA(wfr[kk], afr[rt][kk], acc);
          int n = w * 32 + rt * 16 + cI;
          int c0 = ct * 16 + gI * 4;
          int h = c0 >> 5, d0 = c0 & 31;
          bf16x4 o4;
          if (mat == 0) {
#pragma unroll
            for (int r = 0; r < 4; r++) o4[r] = (bf16)((acc[r] + bv4[r]) * QSCALE);
          } else {
#pragma unroll
            for (int r = 0; r < 4; r++) o4[r] = (bf16)(acc[r] + bv4[r]);
          }
          *(bf16x4*)(dst + ((size_t)(b * 6 + h) * 256 + n) * 32 + d0) = o4;
        }
      } else {
        float bv = b_qkv[384 + ct * 16 + cI];
        int c = ct * 16 + cI, h = c >> 5, d = c & 31;
#pragma unroll
        for (int rt = 0; rt < 2; rt++) {
          f32x4 acc = {0.f, 0.f, 0.f, 0.f};
#pragma unroll
          for (int kk = 0; kk < 6; kk++) acc = MFMA(afr[rt][kk], wfr[kk], acc);
          int n0 = w * 32 + rt * 16 + gI * 4;
          bf16x4 o4;
#pragma unroll
          for (int r = 0; r < 4; r++) o4[r] = (bf16)(acc[r] + bv);
          *(bf16x4*)(vwT + ((size_t)(b * 6 + h) * 32 + d) * 256 + n0) = o4;
        }
      }
    }
  }
}

// ---------------------------------------------------------------------------
// Kernel C: flash attention, 32x32 MFMA, zero LDS, no-max softmax.
// grid 1536 (b,h), 4 waves x 2 subtiles, K/V frags shared across subtiles.
// Interleaved subtile chains + 1-deep K/bias prefetch (R18/R19).
// P-packing via plain (bf16) casts -- compiler emits its own cvt_pk
// (m240: hand-written cvt_pk asm + unions force reg constraints / scratch).
// P = exp2(S); scalar l; sigma-permuted PV.  launch_bounds(256,2): no spill.
// ---------------------------------------------------------------------------
__global__ __launch_bounds__(256, 2) void attn_kernel(
    const bf16* __restrict__ qw, const bf16* __restrict__ kw,
    const bf16* __restrict__ vwT, const _Float16* __restrict__ maskp,
    const _Float16* __restrict__ pos16, bf16* __restrict__ ctx) {
  const int tid = threadIdx.x;
  const int bid = blockIdx.x;
  const int s_ = bid & 63, j_ = bid >> 6;          // mask slice; XCD = bid%8 = s_%8
  const int g_ = j_ & 3, h = j_ >> 2;
  const int b = g_ * 64 + s_;

  const bf16* qb = qw  + (size_t)(b * 6 + h) * 8192;
  const bf16* kb = kw  + (size_t)(b * 6 + h) * 8192;
  const bf16* vb = vwT + (size_t)(b * 6 + h) * 8192;
  const _Float16* pg = pos16 + (size_t)h * (31 * 512);

  const int lane = tid & 63, w = tid >> 6;
  const int q5 = lane & 31, hi = lane >> 5;

  bf16x8 qf[2][2];
#pragma unroll
  for (int sub = 0; sub < 2; sub++) {
    int qa = w * 64 + sub * 32 + q5;
    qf[sub][0] = *(const bf16x8*)(qb + qa * 32 + hi * 8);
    qf[sub][1] = *(const bf16x8*)(qb + qa * 32 + 16 + hi * 8);
  }

  f32x16 o[2];
  float l[2];
#pragma unroll
  for (int sub = 0; sub < 2; sub++) {
#pragma unroll
    for (int r = 0; r < 16; r++) o[sub][r] = 0.f;
    l[sub] = 0.f;
  }

  // ---- pipeline state: K frags + combined f16 bias for current/next ----
  bf16x8 kf0c, kf1c, kf0n, kf1n;
  f16x8 bb0c[2], bb1c[2], bb0n[2], bb1n[2];

#define PF(MT)                                                                \
  do {                                                                        \
    const int m0_ = (MT) * 32;                                                \
    kf0n = *(const bf16x8*)(kb + (m0_ + q5) * 32 + hi * 8);                   \
    kf1n = *(const bf16x8*)(kb + (m0_ + q5) * 32 + 16 + hi * 8);              \
    _Pragma("unroll")                                                         \
    for (int sub_ = 0; sub_ < 2; sub_++) {                                    \
      const int qa_ = w * 64 + sub_ * 32 + q5;                                \
      const int rd0_ = (qa_ >> 4) - 2 * (MT) + 15;                            \
      f16x8 plo_ = *(const f16x8*)(pg + ((size_t)rd0_ * 64 + lane) * 8);      \
      f16x8 phi_ = *(const f16x8*)(pg + ((size_t)(rd0_ - 1) * 64 + lane) * 8);\
      const _Float16* mrow_ =                                                 \
          maskp + ((((size_t)s_ * 8 + (w * 2 + sub_)) * 8 + (MT)) * 64 +      \
                   lane) * 16;                                                \
      f16x8 mk0_ = *(const f16x8*)(mrow_);                                    \
      f16x8 mk1_ = *(const f16x8*)(mrow_ + 8);                                \
      bb0n[sub_] = mk0_ + plo_;                                               \
      bb1n[sub_] = mk1_ + phi_;                                               \
    }                                                                         \
  } while (0)

  PF(0);
  kf0c = kf0n; kf1c = kf1n;
  bb0c[0] = bb0n[0]; bb0c[1] = bb0n[1];
  bb1c[0] = bb1n[0]; bb1c[1] = bb1n[1];

#pragma unroll
  for (int mt = 0; mt < 8; mt++) {
    // V loads for current iteration (consumed after the exp chain)
    const bf16* vrow = vb + q5 * 256 + mt * 32 + 4 * hi;
    bf16x4 v00 = *(const bf16x4*)(vrow);
    bf16x4 v01 = *(const bf16x4*)(vrow + 8);
    bf16x4 v10 = *(const bf16x4*)(vrow + 16);
    bf16x4 v11 = *(const bf16x4*)(vrow + 24);
    // prefetch next iteration's K + bias (in flight during this compute)
    if (mt < 7) PF(mt + 1);

    bf16x8 vf0, vf1;
#pragma unroll
    for (int j2 = 0; j2 < 4; j2++) {
      vf0[j2] = v00[j2]; vf0[4 + j2] = v01[j2];
      vf1[j2] = v10[j2]; vf1[4 + j2] = v11[j2];
    }

    // ---- phase 1: BOTH subs' QK MFMAs issued back-to-back ----
    f32x16 sa0, sa1;
#pragma unroll
    for (int r = 0; r < 8; r++)  { sa0[r] = (float)bb0c[0][r];
                                   sa1[r] = (float)bb0c[1][r]; }
#pragma unroll
    for (int r = 0; r < 8; r++)  { sa0[8 + r] = (float)bb1c[0][r];
                                   sa1[8 + r] = (float)bb1c[1][r]; }
    __builtin_amdgcn_s_setprio(1);
    sa0 = MFMA32(kf0c, qf[0][0], sa0);
    sa0 = MFMA32(kf1c, qf[0][1], sa0);
    sa1 = MFMA32(kf0c, qf[1][0], sa1);
    sa1 = MFMA32(kf1c, qf[1][1], sa1);
    __builtin_amdgcn_s_setprio(0);

    // ---- phase 2: both softmax/cvt chains (VALU; overlaps MFMA tails) ----
    float ls0 = 0.f, ls1 = 0.f;
#pragma unroll
    for (int r = 0; r < 16; r++) {
      float p0 = exp2f(sa0[r]); sa0[r] = p0; ls0 += p0;
      float p1 = exp2f(sa1[r]); sa1[r] = p1; ls1 += p1;
    }
    ls0 += __shfl_xor(ls0, 32); l[0] += ls0;
    ls1 += __shfl_xor(ls1, 32); l[1] += ls1;

    // P -> bf16 A-frags via plain casts (compiler emits cvt_pk; m240)
    bf16x8 pa1[2], pa2[2];
#pragma unroll
    for (int j = 0; j < 8; j++) {
      pa1[0][j] = (bf16)sa0[j];
      pa2[0][j] = (bf16)sa0[8 + j];
      pa1[1][j] = (bf16)sa1[j];
      pa2[1][j] = (bf16)sa1[8 + j];
    }

    // ---- phase 3: both PV clusters ----
    __builtin_amdgcn_s_setprio(1);
    o[0] = MFMA32(pa1[0], vf0, o[0]);
    o[0] = MFMA32(pa2[0], vf1, o[0]);
    o[1] = MFMA32(pa1[1], vf0, o[1]);
    o[1] = MFMA32(pa2[1], vf1, o[1]);
    __builtin_amdgcn_s_setprio(0);

    // rotate pipeline (full unroll -> pure register renames)
    kf0c = kf0n; kf1c = kf1n;
    bb0c[0] = bb0n[0]; bb0c[1] = bb0n[1];
    bb1c[0] = bb1n[0]; bb1c[1] = bb1n[1];
  }
#undef PF

  // epilogue: l at lane q (col); o rows need l[q_local] -> shuffle
#pragma unroll
  for (int sub = 0; sub < 2; sub++) {
    float linv = 1.0f / l[sub];
#pragma unroll
    for (int r = 0; r < 16; r++) {
      int q_local = (r & 3) + 8 * (r >> 2) + 4 * hi;
      float lv = __shfl(linv, q_local);
      int qa = w * 64 + sub * 32 + q_local;
      ctx[((size_t)(b << 8) + qa) * 192 + h * 32 + q5] = (bf16)(o[sub][r] * lv);
    }
  }
}

// ---------------------------------------------------------------------------
// Kernel D: out = ctx @ w_proj + b_proj.  grid 256, 512 thr / 8 waves x 32
// rows (BM=256, rt=2), W^T staged in LDS.
// ---------------------------------------------------------------------------
#define SMEM_C (192 * 200 * 2)

__global__ __launch_bounds__(512) void proj_kernel(
    const bf16* __restrict__ ctx, const bf16* __restrict__ wpT,
    const float* __restrict__ b_proj, float* __restrict__ out) {
  extern __shared__ char smem[];
  bf16* wt = (bf16*)smem;   // [192 c][200 k]
  const int tid = threadIdx.x;
#pragma unroll
  for (int it = 0; it < 9; it++) {
    int idx = it * 512 + tid;
    int c = idx / 24, ch = idx % 24;
    bf16x8 v8 = *(const bf16x8*)(wpT + (size_t)c * 192 + ch * 8);
    *(bf16x8*)(wt + c * 200 + ch * 8) = v8;
  }
  __syncthreads();
  const int lane = tid & 63, w = tid >> 6;          // w in 0..7
  const int cI = lane & 15, gI = lane >> 4;
  const int row0 = blockIdx.x * 256 + w * 32;
  bf16x8 afr[2][6];
#pragma unroll
  for (int rt = 0; rt < 2; rt++) {
#pragma unroll
    for (int kk = 0; kk < 6; kk++)
      afr[rt][kk] = *(const bf16x8*)(ctx + (size_t)(row0 + rt * 16 + cI) * 192 +
                                     kk * 32 + gI * 8);
  }
#pragma unroll
  for (int ct = 0; ct < 12; ct++) {
    bf16x8 wfr[6];
#pragma unroll
    for (int kk = 0; kk < 6; kk++)
      wfr[kk] = *(const bf16x8*)(wt + (ct * 16 + cI) * 200 + kk * 32 + gI * 8);
    f32x4 bv4 = *(const f32x4*)(b_proj + ct * 16 + gI * 4);
#pragma unroll
    for (int rt = 0; rt < 2; rt++) {
      f32x4 acc = {0.f, 0.f, 0.f, 0.f};
#pragma unroll
      for (int kk = 0; kk < 6; kk++) acc = MFMA(wfr[kk], afr[rt][kk], acc);
      f32x4 res;
#pragma unroll
      for (int r = 0; r < 4; r++) res[r] = acc[r] + bv4[r];
      *(f32x4*)(out + (size_t)(row0 + rt * 16 + cI) * 192 + ct * 16 + gI * 4) = res;
    }
  }
}

// ---------------------------------------------------------------------------
extern "C" void kernel_launch(void* const* d_in, const int* in_sizes, int n_in,
                              void* d_out, int out_size, void* d_ws, size_t ws_size,
                              hipStream_t stream) {
  (void)in_sizes; (void)n_in; (void)out_size; (void)ws_size;
  const float* x      = (const float*)d_in[0];
  const float* mask   = (const float*)d_in[1];
  const float* w_qkv  = (const float*)d_in[2];
  const float* b_qkv  = (const float*)d_in[3];
  const float* w_proj = (const float*)d_in[4];
  const float* b_proj = (const float*)d_in[5];
  const float* pw0    = (const float*)d_in[6];
  const float* pb0    = (const float*)d_in[7];
  const float* g1     = (const float*)d_in[8];
  const float* be1    = (const float*)d_in[9];
  const float* w1     = (const float*)d_in[10];
  const float* b1     = (const float*)d_in[11];
  const float* g2     = (const float*)d_in[12];
  const float* be2    = (const float*)d_in[13];
  const float* w2     = (const float*)d_in[14];
  const float* b2     = (const float*)d_in[15];
  const float* g3     = (const float*)d_in[16];
  const float* be3    = (const float*)d_in[17];
  const float* w3     = (const float*)d_in[18];
  const float* b3     = (const float*)d_in[19];

  // ws layout (peak ~96.5 MB):
  //   wqT   @ 0         (221184)   bf16 [576][192]
  //   wpT   @ 221184    (73728)    bf16 [192][192]
  //   pos16 @ 294912    (190464)   f16 [6][31][64][8]  (*log2e)
  //   qw    @ 485376    (25165824) bf16 [b][h][n][32]  (pre-scaled s*log2e)
  //   kw    @ 25651200  (25165824)
  //   vwT   @ 50817024  (25165824) bf16 [b][h][32][n]
  //   ctx   @ 75982848  (25165824)
  // maskp (f16 [64][8][8][64][16] = 8,388,608 B) lives in d_out (50 MB);
  // proj_kernel fully overwrites d_out afterwards.
  char* ws = (char*)d_ws;
  bf16*  wqT    = (bf16*)(ws);
  bf16*  wpT    = (bf16*)(ws + 221184);
  _Float16* pos16 = (_Float16*)(ws + 294912);
  bf16*  qw     = (bf16*)(ws + 485376);
  bf16*  kw     = (bf16*)(ws + 25651200);
  bf16*  vwT    = (bf16*)(ws + 50817024);
  bf16*  ctx    = (bf16*)(ws + 75982848);
  _Float16* maskp = (_Float16*)d_out;
  float* outp   = (float*)d_out;

  hipFuncSetAttribute((const void*)qkv_gemm_kernel,
                      hipFuncAttributeMaxDynamicSharedMemorySize, SMEM_G);
  hipFuncSetAttribute((const void*)proj_kernel,
                      hipFuncAttributeMaxDynamicSharedMemorySize, SMEM_C);

  prep_kernel<<<dim3(8954), dim3(256), 0, stream>>>(
      w_qkv, w_proj, mask,
      pw0, pb0, g1, be1, w1, b1, g2, be2, w2, b2, g3, be3, w3, b3,
      wqT, wpT, maskp, pos16);
  qkv_gemm_kernel<<<dim3(256), dim3(512), SMEM_G, stream>>>(
      x, wqT, b_qkv, qw, kw, vwT);
  attn_kernel<<<dim3(1536), dim3(256), 0, stream>>>(
      qw, kw, vwT, maskp, pos16, ctx);
  proj_kernel<<<dim3(256), dim3(512), SMEM_C, stream>>>(
      ctx, wpT, b_proj, outp);
}

// Round 21
// 112.454 us; speedup vs baseline: 1.0361x; 1.0361x over previous
//
#include <hip/hip_runtime.h>
#include <hip/hip_bf16.h>
#include <math.h>

typedef __bf16 bf16;
typedef __bf16 bf16x8 __attribute__((ext_vector_type(8)));
typedef __bf16 bf16x4 __attribute__((ext_vector_type(4)));
typedef float  f32x4  __attribute__((ext_vector_type(4)));
typedef float  f32x16 __attribute__((ext_vector_type(16)));
typedef _Float16 f16x8 __attribute__((ext_vector_type(8)));

#define MFMA(a, b, c)   __builtin_amdgcn_mfma_f32_16x16x32_bf16((a), (b), (c), 0, 0, 0)
#define MFMA32(a, b, c) __builtin_amdgcn_mfma_f32_32x32x16_bf16((a), (b), (c), 0, 0, 0)
#define LOG2E 1.4426950408889634f
// raw v_exp_f32: exact for our score range S in [-30, +10] (no denormals)
#define EXP2R(x) __builtin_amdgcn_exp2f(x)

// ---------------------------------------------------------------------------
// Kernel P: all prep, fully parallel uniform blocks.
//   blocks 0..575      : precast w_qkv^T -> wqT, w_proj^T -> wpT (bf16)
//   blocks 576..8767   : lane-permuted f16 mask table maskp (*log2e)
//   blocks 8768..8953  : pos MLP + lane-permuted f16 pos table (31 rd x 6 h)
// ---------------------------------------------------------------------------
__global__ __launch_bounds__(256) void prep_kernel(
    const float* __restrict__ w_qkv, const float* __restrict__ w_proj,
    const float* __restrict__ mask,
    const float* __restrict__ pw0, const float* __restrict__ pb0,
    const float* __restrict__ g1,  const float* __restrict__ be1,
    const float* __restrict__ w1,  const float* __restrict__ b1,
    const float* __restrict__ g2,  const float* __restrict__ be2,
    const float* __restrict__ w2,  const float* __restrict__ b2,
    const float* __restrict__ g3,  const float* __restrict__ be3,
    const float* __restrict__ w3,  const float* __restrict__ b3,
    bf16* __restrict__ wqT, bf16* __restrict__ wpT,
    _Float16* __restrict__ maskp, _Float16* __restrict__ pos16) {
  __shared__ float posh[31];
  const int blk = blockIdx.x;
  const int t = threadIdx.x;
  if (blk < 576) {
    int idx = blk * 256 + t;
    if (idx < 576 * 192) {
      int c = idx / 192, k = idx % 192;
      wqT[idx] = (bf16)w_qkv[k * 576 + c];
    } else {
      int i2 = idx - 576 * 192;
      int c = i2 / 192, k = i2 % 192;
      wpT[i2] = (bf16)w_proj[k * 192 + c];
    }
  } else if (blk < 8768) {
    size_t e = ((size_t)(blk - 576) * 256 + t) * 2;
    int j  = (int)(e & 15);
    int L  = (int)((e >> 4) & 63);
    int mt = (int)((e >> 10) & 7);
    int qt = (int)((e >> 13) & 7);
    int s  = (int)(e >> 16);
    int q  = qt * 32 + (L & 31);
    int m  = mt * 32 + 16 * (j >> 3) + 8 * ((j >> 2) & 1) + 4 * (L >> 5) + (j & 3);
    const float* src = mask + ((size_t)s * 256 + q) * 256 + m;
    maskp[e]     = (_Float16)(src[0] * LOG2E);
    maskp[e + 1] = (_Float16)(src[1] * LOG2E);
  } else {
    const int pb = blk - 8768;                     // 0..185
    const int rd = pb % 31, h = pb / 31;
    if (t < 31) {
      int i = rd * 31 + t;
      float bh = (float)(i / 31) - 15.0f;
      float bw = (float)(i % 31) - 15.0f;
      float xv[12];
#pragma unroll
      for (int j = 0; j < 12; j++) xv[j] = bh * pw0[j] + bw * pw0[12 + j] + pb0[j];
      const float* G[3]  = {g1, g2, g3};
      const float* BE[3] = {be1, be2, be3};
      const float* W[3]  = {w1, w2, w3};
      const float* BB[3] = {b1, b2, b3};
#pragma unroll
      for (int s = 0; s < 3; s++) {
        float m = 0.f;
#pragma unroll
        for (int j = 0; j < 12; j++) m += xv[j];
        m *= (1.0f / 12.0f);
        float v = 0.f;
#pragma unroll
        for (int j = 0; j < 12; j++) { float d = xv[j] - m; v += d * d; }
        v *= (1.0f / 12.0f);
        float inv = 1.0f / sqrtf(v + 1e-5f);
        float y[12];
#pragma unroll
        for (int j = 0; j < 12; j++) {
          float tt = (xv[j] - m) * inv * G[s][j] + BE[s][j];
          y[j] = tt > 0.f ? tt : 0.f;
        }
        int oc = (s == 2) ? 6 : 12;
        float on[12];
        for (int c = 0; c < oc; c++) {
          float acc = BB[s][c];
#pragma unroll
          for (int j = 0; j < 12; j++) acc += y[j] * W[s][j * oc + c];
          on[c] = acc;
        }
        for (int c = 0; c < 12; c++) xv[c] = (c < oc) ? on[c] : 0.f;
      }
      posh[t] = xv[h];
    }
    __syncthreads();
    for (int e = t; e < 512; e += 256) {
      int L = e >> 3, j = e & 7;
      int idx = (L & 15) - ((j & 3) + 8 * (j >> 2) + 4 * (L >> 5)) + 15;  // 0..30
      pos16[((h * 31 + rd) * 64 + L) * 8 + j] = (_Float16)(posh[idx] * LOG2E);
    }
  }
}

// ---------------------------------------------------------------------------
// Kernel B: QKV GEMM.  grid 256, 512 thr / 8 waves x 32 rows (BM=256, rt=2).
// ---------------------------------------------------------------------------
#define SMEM_G (192 * 200 * 2)

__global__ __launch_bounds__(512) void qkv_gemm_kernel(
    const float* __restrict__ x, const bf16* __restrict__ wqT,
    const float* __restrict__ b_qkv, bf16* __restrict__ qw,
    bf16* __restrict__ kw, bf16* __restrict__ vwT) {
  extern __shared__ char smem[];
  bf16* wt = (bf16*)smem;   // [192 c][200 k]
  const int tid = threadIdx.x;
  const int lane = tid & 63, w = tid >> 6;          // w in 0..7
  const int cI = lane & 15, gI = lane >> 4;
  const int b = blockIdx.x;                         // 256 rows = 1 window
  const int row0 = b * 256 + w * 32;
  const float QSCALE = 0.17677669529663687f * LOG2E;

  bf16x8 afr[2][6];
#pragma unroll
  for (int rt = 0; rt < 2; rt++) {
#pragma unroll
    for (int kk = 0; kk < 6; kk++) {
      const float* p = x + (size_t)(row0 + rt * 16 + cI) * 192 + kk * 32 + gI * 8;
      float4 f0 = *(const float4*)p;
      float4 f1 = *(const float4*)(p + 4);
      bf16x8 a;
      a[0] = (bf16)f0.x; a[1] = (bf16)f0.y; a[2] = (bf16)f0.z; a[3] = (bf16)f0.w;
      a[4] = (bf16)f1.x; a[5] = (bf16)f1.y; a[6] = (bf16)f1.z; a[7] = (bf16)f1.w;
      afr[rt][kk] = a;
    }
  }

#pragma unroll
  for (int mat = 0; mat < 3; mat++) {
    __syncthreads();
#pragma unroll
    for (int it = 0; it < 9; it++) {
      int idx = it * 512 + tid;                     // 192 rows x 24 chunks
      int c = idx / 24, ch = idx % 24;
      bf16x8 v8 = *(const bf16x8*)(wqT + (size_t)(mat * 192 + c) * 192 + ch * 8);
      *(bf16x8*)(wt + c * 200 + ch * 8) = v8;
    }
    __syncthreads();
#pragma unroll
    for (int ct = 0; ct < 12; ct++) {
      bf16x8 wfr[6];
#pragma unroll
      for (int kk = 0; kk < 6; kk++)
        wfr[kk] = *(const bf16x8*)(wt + (ct * 16 + cI) * 200 + kk * 32 + gI * 8);
      if (mat < 2) {
        f32x4 bv4 = *(const f32x4*)(b_qkv + mat * 192 + ct * 16 + gI * 4);
        bf16* dst = (mat == 0) ? qw : kw;
#pragma unroll
        for (int rt = 0; rt < 2; rt++) {
          f32x4 acc = {0.f, 0.f, 0.f, 0.f};
#pragma unroll
          for (int kk = 0; kk < 6; kk++) acc = MFMA(wfr[kk], afr[rt][kk], acc);
          int n = w * 32 + rt * 16 + cI;
          int c0 = ct * 16 + gI * 4;
          int h = c0 >> 5, d0 = c0 & 31;
          bf16x4 o4;
          if (mat == 0) {
#pragma unroll
            for (int r = 0; r < 4; r++) o4[r] = (bf16)((acc[r] + bv4[r]) * QSCALE);
          } else {
#pragma unroll
            for (int r = 0; r < 4; r++) o4[r] = (bf16)(acc[r] + bv4[r]);
          }
          *(bf16x4*)(dst + ((size_t)(b * 6 + h) * 256 + n) * 32 + d0) = o4;
        }
      } else {
        float bv = b_qkv[384 + ct * 16 + cI];
        int c = ct * 16 + cI, h = c >> 5, d = c & 31;
#pragma unroll
        for (int rt = 0; rt < 2; rt++) {
          f32x4 acc = {0.f, 0.f, 0.f, 0.f};
#pragma unroll
          for (int kk = 0; kk < 6; kk++) acc = MFMA(afr[rt][kk], wfr[kk], acc);
          int n0 = w * 32 + rt * 16 + gI * 4;
          bf16x4 o4;
#pragma unroll
          for (int r = 0; r < 4; r++) o4[r] = (bf16)(acc[r] + bv);
          *(bf16x4*)(vwT + ((size_t)(b * 6 + h) * 32 + d) * 256 + n0) = o4;
        }
      }
    }
  }
}

// ---------------------------------------------------------------------------
// Kernel C: flash attention, 32x32 MFMA, zero LDS, no-max softmax.
// grid 1536 (b,h), 4 waves x 2 subtiles, K/V frags shared across subtiles.
// Interleaved subtile chains + 1-deep K/bias prefetch (R18/R19).
// P = 2^S via RAW v_exp_f32 (exact on S in [-30,10]; avoids the ocml
// denormal-fixup expansion -- the 5x VALU-census anomaly suspect).
// Scalar l; sigma-permuted PV.  launch_bounds(256,2): no spill.
// ---------------------------------------------------------------------------
__global__ __launch_bounds__(256, 2) void attn_kernel(
    const bf16* __restrict__ qw, const bf16* __restrict__ kw,
    const bf16* __restrict__ vwT, const _Float16* __restrict__ maskp,
    const _Float16* __restrict__ pos16, bf16* __restrict__ ctx) {
  const int tid = threadIdx.x;
  const int bid = blockIdx.x;
  const int s_ = bid & 63, j_ = bid >> 6;          // mask slice; XCD = bid%8 = s_%8
  const int g_ = j_ & 3, h = j_ >> 2;
  const int b = g_ * 64 + s_;

  const bf16* qb = qw  + (size_t)(b * 6 + h) * 8192;
  const bf16* kb = kw  + (size_t)(b * 6 + h) * 8192;
  const bf16* vb = vwT + (size_t)(b * 6 + h) * 8192;
  const _Float16* pg = pos16 + (size_t)h * (31 * 512);

  const int lane = tid & 63, w = tid >> 6;
  const int q5 = lane & 31, hi = lane >> 5;

  bf16x8 qf[2][2];
#pragma unroll
  for (int sub = 0; sub < 2; sub++) {
    int qa = w * 64 + sub * 32 + q5;
    qf[sub][0] = *(const bf16x8*)(qb + qa * 32 + hi * 8);
    qf[sub][1] = *(const bf16x8*)(qb + qa * 32 + 16 + hi * 8);
  }

  f32x16 o[2];
  float l[2];
#pragma unroll
  for (int sub = 0; sub < 2; sub++) {
#pragma unroll
    for (int r = 0; r < 16; r++) o[sub][r] = 0.f;
    l[sub] = 0.f;
  }

  // ---- pipeline state: K frags + combined f16 bias for current/next ----
  bf16x8 kf0c, kf1c, kf0n, kf1n;
  f16x8 bb0c[2], bb1c[2], bb0n[2], bb1n[2];

#define PF(MT)                                                                \
  do {                                                                        \
    const int m0_ = (MT) * 32;                                                \
    kf0n = *(const bf16x8*)(kb + (m0_ + q5) * 32 + hi * 8);                   \
    kf1n = *(const bf16x8*)(kb + (m0_ + q5) * 32 + 16 + hi * 8);              \
    _Pragma("unroll")                                                         \
    for (int sub_ = 0; sub_ < 2; sub_++) {                                    \
      const int qa_ = w * 64 + sub_ * 32 + q5;                                \
      const int rd0_ = (qa_ >> 4) - 2 * (MT) + 15;                            \
      f16x8 plo_ = *(const f16x8*)(pg + ((size_t)rd0_ * 64 + lane) * 8);      \
      f16x8 phi_ = *(const f16x8*)(pg + ((size_t)(rd0_ - 1) * 64 + lane) * 8);\
      const _Float16* mrow_ =                                                 \
          maskp + ((((size_t)s_ * 8 + (w * 2 + sub_)) * 8 + (MT)) * 64 +      \
                   lane) * 16;                                                \
      f16x8 mk0_ = *(const f16x8*)(mrow_);                                    \
      f16x8 mk1_ = *(const f16x8*)(mrow_ + 8);                                \
      bb0n[sub_] = mk0_ + plo_;                                               \
      bb1n[sub_] = mk1_ + phi_;                                               \
    }                                                                         \
  } while (0)

  PF(0);
  kf0c = kf0n; kf1c = kf1n;
  bb0c[0] = bb0n[0]; bb0c[1] = bb0n[1];
  bb1c[0] = bb1n[0]; bb1c[1] = bb1n[1];

#pragma unroll
  for (int mt = 0; mt < 8; mt++) {
    // V loads for current iteration (consumed after the exp chain)
    const bf16* vrow = vb + q5 * 256 + mt * 32 + 4 * hi;
    bf16x4 v00 = *(const bf16x4*)(vrow);
    bf16x4 v01 = *(const bf16x4*)(vrow + 8);
    bf16x4 v10 = *(const bf16x4*)(vrow + 16);
    bf16x4 v11 = *(const bf16x4*)(vrow + 24);
    // prefetch next iteration's K + bias (in flight during this compute)
    if (mt < 7) PF(mt + 1);

    bf16x8 vf0, vf1;
#pragma unroll
    for (int j2 = 0; j2 < 4; j2++) {
      vf0[j2] = v00[j2]; vf0[4 + j2] = v01[j2];
      vf1[j2] = v10[j2]; vf1[4 + j2] = v11[j2];
    }

    // ---- phase 1: BOTH subs' QK MFMAs issued back-to-back ----
    f32x16 sa0, sa1;
#pragma unroll
    for (int r = 0; r < 8; r++)  { sa0[r] = (float)bb0c[0][r];
                                   sa1[r] = (float)bb0c[1][r]; }
#pragma unroll
    for (int r = 0; r < 8; r++)  { sa0[8 + r] = (float)bb1c[0][r];
                                   sa1[8 + r] = (float)bb1c[1][r]; }
    __builtin_amdgcn_s_setprio(1);
    sa0 = MFMA32(kf0c, qf[0][0], sa0);
    sa0 = MFMA32(kf1c, qf[0][1], sa0);
    sa1 = MFMA32(kf0c, qf[1][0], sa1);
    sa1 = MFMA32(kf1c, qf[1][1], sa1);
    __builtin_amdgcn_s_setprio(0);

    // ---- phase 2: both softmax/cvt chains (VALU; overlaps MFMA tails) ----
    float ls0 = 0.f, ls1 = 0.f;
#pragma unroll
    for (int r = 0; r < 16; r++) {
      float p0 = EXP2R(sa0[r]); sa0[r] = p0; ls0 += p0;
      float p1 = EXP2R(sa1[r]); sa1[r] = p1; ls1 += p1;
    }
    ls0 += __shfl_xor(ls0, 32); l[0] += ls0;
    ls1 += __shfl_xor(ls1, 32); l[1] += ls1;

    // P -> bf16 A-frags via plain casts (compiler emits cvt_pk)
    bf16x8 pa1[2], pa2[2];
#pragma unroll
    for (int j = 0; j < 8; j++) {
      pa1[0][j] = (bf16)sa0[j];
      pa2[0][j] = (bf16)sa0[8 + j];
      pa1[1][j] = (bf16)sa1[j];
      pa2[1][j] = (bf16)sa1[8 + j];
    }

    // ---- phase 3: both PV clusters ----
    __builtin_amdgcn_s_setprio(1);
    o[0] = MFMA32(pa1[0], vf0, o[0]);
    o[0] = MFMA32(pa2[0], vf1, o[0]);
    o[1] = MFMA32(pa1[1], vf0, o[1]);
    o[1] = MFMA32(pa2[1], vf1, o[1]);
    __builtin_amdgcn_s_setprio(0);

    // rotate pipeline (full unroll -> pure register renames)
    kf0c = kf0n; kf1c = kf1n;
    bb0c[0] = bb0n[0]; bb0c[1] = bb0n[1];
    bb1c[0] = bb1n[0]; bb1c[1] = bb1n[1];
  }
#undef PF

  // epilogue: l at lane q (col); o rows need l[q_local] -> shuffle
#pragma unroll
  for (int sub = 0; sub < 2; sub++) {
    float linv = 1.0f / l[sub];
#pragma unroll
    for (int r = 0; r < 16; r++) {
      int q_local = (r & 3) + 8 * (r >> 2) + 4 * hi;
      float lv = __shfl(linv, q_local);
      int qa = w * 64 + sub * 32 + q_local;
      ctx[((size_t)(b << 8) + qa) * 192 + h * 32 + q5] = (bf16)(o[sub][r] * lv);
    }
  }
}

// ---------------------------------------------------------------------------
// Kernel D: out = ctx @ w_proj + b_proj.  grid 256, 512 thr / 8 waves x 32
// rows (BM=256, rt=2), W^T staged in LDS.
// ---------------------------------------------------------------------------
#define SMEM_C (192 * 200 * 2)

__global__ __launch_bounds__(512) void proj_kernel(
    const bf16* __restrict__ ctx, const bf16* __restrict__ wpT,
    const float* __restrict__ b_proj, float* __restrict__ out) {
  extern __shared__ char smem[];
  bf16* wt = (bf16*)smem;   // [192 c][200 k]
  const int tid = threadIdx.x;
#pragma unroll
  for (int it = 0; it < 9; it++) {
    int idx = it * 512 + tid;
    int c = idx / 24, ch = idx % 24;
    bf16x8 v8 = *(const bf16x8*)(wpT + (size_t)c * 192 + ch * 8);
    *(bf16x8*)(wt + c * 200 + ch * 8) = v8;
  }
  __syncthreads();
  const int lane = tid & 63, w = tid >> 6;          // w in 0..7
  const int cI = lane & 15, gI = lane >> 4;
  const int row0 = blockIdx.x * 256 + w * 32;
  bf16x8 afr[2][6];
#pragma unroll
  for (int rt = 0; rt < 2; rt++) {
#pragma unroll
    for (int kk = 0; kk < 6; kk++)
      afr[rt][kk] = *(const bf16x8*)(ctx + (size_t)(row0 + rt * 16 + cI) * 192 +
                                     kk * 32 + gI * 8);
  }
#pragma unroll
  for (int ct = 0; ct < 12; ct++) {
    bf16x8 wfr[6];
#pragma unroll
    for (int kk = 0; kk < 6; kk++)
      wfr[kk] = *(const bf16x8*)(wt + (ct * 16 + cI) * 200 + kk * 32 + gI * 8);
    f32x4 bv4 = *(const f32x4*)(b_proj + ct * 16 + gI * 4);
#pragma unroll
    for (int rt = 0; rt < 2; rt++) {
      f32x4 acc = {0.f, 0.f, 0.f, 0.f};
#pragma unroll
      for (int kk = 0; kk < 6; kk++) acc = MFMA(wfr[kk], afr[rt][kk], acc);
      f32x4 res;
#pragma unroll
      for (int r = 0; r < 4; r++) res[r] = acc[r] + bv4[r];
      *(f32x4*)(out + (size_t)(row0 + rt * 16 + cI) * 192 + ct * 16 + gI * 4) = res;
    }
  }
}

// ---------------------------------------------------------------------------
extern "C" void kernel_launch(void* const* d_in, const int* in_sizes, int n_in,
                              void* d_out, int out_size, void* d_ws, size_t ws_size,
                              hipStream_t stream) {
  (void)in_sizes; (void)n_in; (void)out_size; (void)ws_size;
  const float* x      = (const float*)d_in[0];
  const float* mask   = (const float*)d_in[1];
  const float* w_qkv  = (const float*)d_in[2];
  const float* b_qkv  = (const float*)d_in[3];
  const float* w_proj = (const float*)d_in[4];
  const float* b_proj = (const float*)d_in[5];
  const float* pw0    = (const float*)d_in[6];
  const float* pb0    = (const float*)d_in[7];
  const float* g1     = (const float*)d_in[8];
  const float* be1    = (const float*)d_in[9];
  const float* w1     = (const float*)d_in[10];
  const float* b1     = (const float*)d_in[11];
  const float* g2     = (const float*)d_in[12];
  const float* be2    = (const float*)d_in[13];
  const float* w2     = (const float*)d_in[14];
  const float* b2     = (const float*)d_in[15];
  const float* g3     = (const float*)d_in[16];
  const float* be3    = (const float*)d_in[17];
  const float* w3     = (const float*)d_in[18];
  const float* b3     = (const float*)d_in[19];

  // ws layout (peak ~96.5 MB):
  //   wqT   @ 0         (221184)   bf16 [576][192]
  //   wpT   @ 221184    (73728)    bf16 [192][192]
  //   pos16 @ 294912    (190464)   f16 [6][31][64][8]  (*log2e)
  //   qw    @ 485376    (25165824) bf16 [b][h][n][32]  (pre-scaled s*log2e)
  //   kw    @ 25651200  (25165824)
  //   vwT   @ 50817024  (25165824) bf16 [b][h][32][n]
  //   ctx   @ 75982848  (25165824)
  // maskp (f16 [64][8][8][64][16] = 8,388,608 B) lives in d_out (50 MB);
  // proj_kernel fully overwrites d_out afterwards.
  char* ws = (char*)d_ws;
  bf16*  wqT    = (bf16*)(ws);
  bf16*  wpT    = (bf16*)(ws + 221184);
  _Float16* pos16 = (_Float16*)(ws + 294912);
  bf16*  qw     = (bf16*)(ws + 485376);
  bf16*  kw     = (bf16*)(ws + 25651200);
  bf16*  vwT    = (bf16*)(ws + 50817024);
  bf16*  ctx    = (bf16*)(ws + 75982848);
  _Float16* maskp = (_Float16*)d_out;
  float* outp   = (float*)d_out;

  hipFuncSetAttribute((const void*)qkv_gemm_kernel,
                      hipFuncAttributeMaxDynamicSharedMemorySize, SMEM_G);
  hipFuncSetAttribute((const void*)proj_kernel,
                      hipFuncAttributeMaxDynamicSharedMemorySize, SMEM_C);

  prep_kernel<<<dim3(8954), dim3(256), 0, stream>>>(
      w_qkv, w_proj, mask,
      pw0, pb0, g1, be1, w1, b1, g2, be2, w2, b2, g3, be3, w3, b3,
      wqT, wpT, maskp, pos16);
  qkv_gemm_kernel<<<dim3(256), dim3(512), SMEM_G, stream>>>(
      x, wqT, b_qkv, qw, kw, vwT);
  attn_kernel<<<dim3(1536), dim3(256), 0, stream>>>(
      qw, kw, vwT, maskp, pos16, ctx);
  proj_kernel<<<dim3(256), dim3(512), SMEM_C, stream>>>(
      ctx, wpT, b_proj, outp);
}